// Round 2
// baseline (543.910 us; speedup 1.0000x reference)
//
#include <hip/hip_runtime.h>
#include <hip/hip_bf16.h>

// GATNet: 2-layer GAT (H=8, D=16) + linear classifier, fp32.
// CSR-by-dst build (hist + scan + scatter), one wave per dst node for
// segment softmax + aggregation (no float atomics), LDS-tiled fp32 GEMMs.
// NOTE: edge_index arrives as int32 (harness converts integer inputs).

#define FDIM 128   // F = H*D = 128
#define HEADS 8
#define DHEAD 16

__device__ __forceinline__ float leaky02(float x) {
    return fmaxf(x, 0.2f * x);
}

// ---------------- CSR build ----------------

__global__ __launch_bounds__(256) void hist_kernel(const int* __restrict__ ei,
                                                   int* __restrict__ deg,
                                                   int E) {
    int e = blockIdx.x * 256 + threadIdx.x;
    if (e >= E) return;
    int d = ei[E + e];          // dst row of int32 edge_index[2][E]
    atomicAdd(&deg[d], 1);
}

__global__ __launch_bounds__(1024) void scan_kernel(const int* __restrict__ deg,
                                                    int* __restrict__ row_start,
                                                    int* __restrict__ cursor,
                                                    int n) {
    __shared__ int sbuf[1024];
    __shared__ int carry_s;
    int tid = threadIdx.x;
    if (tid == 0) carry_s = 0;
    __syncthreads();
    for (int base = 0; base < n; base += 1024) {
        int i = base + tid;
        int v = (i < n) ? deg[i] : 0;
        sbuf[tid] = v;
        __syncthreads();
        // Hillis-Steele inclusive scan
        for (int off = 1; off < 1024; off <<= 1) {
            int t = (tid >= off) ? sbuf[tid - off] : 0;
            __syncthreads();
            sbuf[tid] += t;
            __syncthreads();
        }
        int incl = sbuf[tid];
        int carry = carry_s;
        if (i < n) {
            int ex = carry + incl - v;   // exclusive
            row_start[i] = ex;
            cursor[i] = ex;
        }
        __syncthreads();
        if (tid == 1023) carry_s = carry + incl;
        __syncthreads();
    }
    if (tid == 0) row_start[n] = carry_s;
}

__global__ __launch_bounds__(256) void scatter_kernel(const int* __restrict__ ei,
                                                      int* __restrict__ cursor,
                                                      int* __restrict__ csr_src,
                                                      int E) {
    int e = blockIdx.x * 256 + threadIdx.x;
    if (e >= E) return;
    int s = ei[e];
    int d = ei[E + e];
    int pos = atomicAdd(&cursor[d], 1);
    csr_src[pos] = s;
}

// ---------------- GEMM: A[n x 128] @ W[128 x M] (+bias) ----------------

template <int M, bool BIAS>
__global__ __launch_bounds__(256) void gemm_k128(const float* __restrict__ A,
                                                 const float* __restrict__ W,
                                                 const float* __restrict__ bias,
                                                 float* __restrict__ out,
                                                 int n) {
    constexpr int CG = M / 4;           // cols per thread (4 col groups)
    __shared__ float xs[64][129];       // +1 pad: avoid same-bank on xs[row][k]
    __shared__ float ws[32][M];
    int tid = threadIdx.x;
    int row0 = blockIdx.x * 64;
    int row = tid & 63;
    int col0 = (tid >> 6) * CG;

    // stage x tile (64 rows x 128 cols), float4, zero-fill tail rows
    for (int idx = tid; idx < 64 * 32; idx += 256) {
        int r = idx >> 5, c4 = idx & 31;
        float4 v = make_float4(0.f, 0.f, 0.f, 0.f);
        if (row0 + r < n) v = *(const float4*)&A[(size_t)(row0 + r) * FDIM + c4 * 4];
        *(float4*)&xs[r][c4 * 4] = v;
    }

    float acc[CG];
#pragma unroll
    for (int j = 0; j < CG; ++j) acc[j] = 0.f;

    for (int kc = 0; kc < 128; kc += 32) {
        __syncthreads();   // xs ready / previous ws consumed
        for (int idx = tid; idx < 32 * M; idx += 256) {
            int kk = idx / M, c = idx % M;
            ws[kk][c] = W[(size_t)(kc + kk) * M + c];
        }
        __syncthreads();
#pragma unroll
        for (int k = 0; k < 32; ++k) {
            float xv = xs[row][kc + k];
#pragma unroll
            for (int j = 0; j < CG; ++j)
                acc[j] += xv * ws[k][col0 + j];   // broadcast across wave
        }
    }

    if (row0 + row < n) {
#pragma unroll
        for (int j = 0; j < CG; ++j) {
            float o = acc[j];
            if (BIAS) o += bias[col0 + j];
            out[(size_t)(row0 + row) * M + col0 + j] = o;
        }
    }
}

// ---------------- attention logits: al[n][h] = sum_d hx[n][h][d]*a[h][d] ----

__global__ __launch_bounds__(256) void al_kernel(const float* __restrict__ hx,
                                                 const float* __restrict__ a_src,
                                                 const float* __restrict__ a_dst,
                                                 float* __restrict__ als,
                                                 float* __restrict__ ald,
                                                 int n) {
    int t = blockIdx.x * 256 + threadIdx.x;
    if (t >= n * HEADS) return;
    int node = t >> 3, h = t & 7;
    float ss = 0.f, sd = 0.f;
#pragma unroll
    for (int d = 0; d < DHEAD; d += 4) {
        float4 hv = *(const float4*)&hx[(size_t)node * FDIM + h * DHEAD + d];
        float4 as = *(const float4*)&a_src[h * DHEAD + d];
        float4 ad = *(const float4*)&a_dst[h * DHEAD + d];
        ss += hv.x * as.x + hv.y * as.y + hv.z * as.z + hv.w * as.w;
        sd += hv.x * ad.x + hv.y * ad.y + hv.z * ad.z + hv.w * ad.w;
    }
    als[t] = ss;
    ald[t] = sd;
}

// ---------------- per-node segment softmax + aggregation ----------------
// One wave (64 lanes) per destination node. lane covers cols {lane, lane+64}.

template <bool DOELU>
__global__ __launch_bounds__(256) void gat_aggregate(const float* __restrict__ hx,
                                                     const float* __restrict__ als,
                                                     const float* __restrict__ ald,
                                                     const int* __restrict__ row_start,
                                                     const int* __restrict__ csr_src,
                                                     const float* __restrict__ bias,
                                                     float* __restrict__ out,
                                                     int n) {
    int wid = threadIdx.x >> 6;
    int lane = threadIdx.x & 63;
    int node = blockIdx.x * 4 + wid;
    if (node >= n) return;

    int rs = row_start[node];
    int deg = row_start[node + 1] - rs;

    int h0 = lane >> 4;        // head for col = lane   (0..3)
    int h1 = 4 + h0;           // head for col = lane+64
    int hr = lane & 7;         // head this lane reduces in phase A

    // ---- phase A: per-head max over incoming edges + self loop ----
    float ald_hr = ald[node * HEADS + hr];
    float mmax = leaky02(als[node * HEADS + hr] + ald_hr);   // self loop
    for (int i = (lane >> 3); i < deg; i += 8) {
        int src = csr_src[rs + i];
        mmax = fmaxf(mmax, leaky02(als[src * HEADS + hr] + ald_hr));
    }
    mmax = fmaxf(mmax, __shfl_xor(mmax, 8));
    mmax = fmaxf(mmax, __shfl_xor(mmax, 16));
    mmax = fmaxf(mmax, __shfl_xor(mmax, 32));
    float m0 = __shfl(mmax, h0);
    float m1 = __shfl(mmax, h1);

    // ---- phase B: weighted gather-accumulate ----
    float ald0 = ald[node * HEADS + h0];
    float ald1 = ald[node * HEADS + h1];
    float acc0 = 0.f, acc1 = 0.f, z0 = 0.f, z1 = 0.f;
    for (int i = 0; i < deg; ++i) {
        int src = csr_src[rs + i];
        float w0 = __expf(leaky02(als[src * HEADS + h0] + ald0) - m0);
        float w1 = __expf(leaky02(als[src * HEADS + h1] + ald1) - m1);
        z0 += w0;
        z1 += w1;
        acc0 += w0 * hx[(size_t)src * FDIM + lane];
        acc1 += w1 * hx[(size_t)src * FDIM + 64 + lane];
    }
    // self loop contribution
    {
        float w0 = __expf(leaky02(als[node * HEADS + h0] + ald0) - m0);
        float w1 = __expf(leaky02(als[node * HEADS + h1] + ald1) - m1);
        z0 += w0;
        z1 += w1;
        acc0 += w0 * hx[(size_t)node * FDIM + lane];
        acc1 += w1 * hx[(size_t)node * FDIM + 64 + lane];
    }

    float o0 = acc0 / z0 + bias[lane];
    float o1 = acc1 / z1 + bias[64 + lane];
    if (DOELU) {
        o0 = o0 > 0.f ? o0 : (__expf(o0) - 1.f);
        o1 = o1 > 0.f ? o1 : (__expf(o1) - 1.f);
    }
    out[(size_t)node * FDIM + lane] = o0;
    out[(size_t)node * FDIM + 64 + lane] = o1;
}

// ---------------- launch ----------------

extern "C" void kernel_launch(void* const* d_in, const int* in_sizes, int n_in,
                              void* d_out, int out_size, void* d_ws, size_t ws_size,
                              hipStream_t stream) {
    const float* x      = (const float*)d_in[0];
    const int*   ei     = (const int*)d_in[1];   // int32 [2][E]
    const float* W1     = (const float*)d_in[2];
    const float* a_src1 = (const float*)d_in[3];
    const float* a_dst1 = (const float*)d_in[4];
    const float* b1     = (const float*)d_in[5];
    const float* W2     = (const float*)d_in[6];
    const float* a_src2 = (const float*)d_in[7];
    const float* a_dst2 = (const float*)d_in[8];
    const float* b2     = (const float*)d_in[9];
    const float* Wc     = (const float*)d_in[10];
    const float* bc     = (const float*)d_in[11];
    float* out = (float*)d_out;

    const int N = in_sizes[0] / FDIM;     // 50000
    const int E = in_sizes[1] / 2;        // 800000

    // workspace layout (~58 MB)
    float* hx   = (float*)d_ws;                  // N*128
    float* hbuf = hx + (size_t)N * FDIM;         // N*128
    float* als  = hbuf + (size_t)N * FDIM;       // N*8
    float* ald  = als + (size_t)N * HEADS;       // N*8
    int* row_start = (int*)(ald + (size_t)N * HEADS);  // N+1
    int* cursor    = row_start + (N + 1);               // N
    int* deg       = cursor + N;                        // N
    int* csr_src   = deg + N;                           // E

    // ---- CSR by dst (shared across both layers) ----
    hipMemsetAsync(deg, 0, (size_t)N * sizeof(int), stream);
    hist_kernel<<<(E + 255) / 256, 256, 0, stream>>>(ei, deg, E);
    scan_kernel<<<1, 1024, 0, stream>>>(deg, row_start, cursor, N);
    scatter_kernel<<<(E + 255) / 256, 256, 0, stream>>>(ei, cursor, csr_src, E);

    const int gemm_grid = (N + 63) / 64;
    const int al_grid   = (N * HEADS + 255) / 256;
    const int agg_grid  = (N + 3) / 4;

    // ---- layer 1 ----
    gemm_k128<128, false><<<gemm_grid, 256, 0, stream>>>(x, W1, nullptr, hx, N);
    al_kernel<<<al_grid, 256, 0, stream>>>(hx, a_src1, a_dst1, als, ald, N);
    gat_aggregate<true><<<agg_grid, 256, 0, stream>>>(hx, als, ald, row_start,
                                                      csr_src, b1, hbuf, N);
    // ---- layer 2 ----
    gemm_k128<128, false><<<gemm_grid, 256, 0, stream>>>(hbuf, W2, nullptr, hx, N);
    al_kernel<<<al_grid, 256, 0, stream>>>(hx, a_src2, a_dst2, als, ald, N);
    gat_aggregate<false><<<agg_grid, 256, 0, stream>>>(hx, als, ald, row_start,
                                                       csr_src, b2, hbuf, N);
    // ---- classifier ----
    gemm_k128<40, true><<<gemm_grid, 256, 0, stream>>>(hbuf, Wc, bc, out, N);
}

// Round 3
// 381.189 us; speedup vs baseline: 1.4269x; 1.4269x over previous
//
#include <hip/hip_runtime.h>
#include <hip/hip_bf16.h>

// GATNet: 2-layer GAT (H=8, D=16) + linear classifier, fp32.
// R3: wave-parallel edge weights (shuffle broadcast), 3-kernel scan,
// register-blocked 4x8 GEMM with transposed x staging.

#define FDIM 128
#define HEADS 8
#define DHEAD 16

__device__ __forceinline__ float leaky02(float x) {
    return fmaxf(x, 0.2f * x);
}

// ---------------- CSR build ----------------

__global__ __launch_bounds__(256) void hist_kernel(const int* __restrict__ ei,
                                                   int* __restrict__ deg,
                                                   int E) {
    int e = blockIdx.x * 256 + threadIdx.x;
    if (e >= E) return;
    atomicAdd(&deg[ei[E + e]], 1);
}

// block b sums deg[b*1024 .. b*1024+1023] -> partials[b]
__global__ __launch_bounds__(256) void scan_partial(const int* __restrict__ deg,
                                                    int* __restrict__ partials,
                                                    int n) {
    __shared__ int red[256];
    int t = threadIdx.x;
    int base = blockIdx.x * 1024 + t * 4;
    int s = 0;
#pragma unroll
    for (int j = 0; j < 4; ++j) {
        int i = base + j;
        if (i < n) s += deg[i];
    }
    red[t] = s;
    __syncthreads();
    for (int off = 128; off > 0; off >>= 1) {
        if (t < off) red[t] += red[t + off];
        __syncthreads();
    }
    if (t == 0) partials[blockIdx.x] = red[0];
}

// single wave: exclusive scan of partials[0..nb), write total to row_start[n]
__global__ __launch_bounds__(64) void scan_offsets(int* __restrict__ partials,
                                                   int* __restrict__ row_start,
                                                   int nb, int n) {
    int lane = threadIdx.x;
    int carry = 0;
    for (int base = 0; base < nb; base += 64) {
        int idx = base + lane;
        int v = (idx < nb) ? partials[idx] : 0;
        int incl = v;
#pragma unroll
        for (int off = 1; off < 64; off <<= 1) {
            int t = __shfl_up(incl, off);
            if (lane >= off) incl += t;
        }
        if (idx < nb) partials[idx] = carry + incl - v;  // exclusive
        carry += __shfl(incl, 63);
    }
    if (lane == 0) row_start[n] = carry;
}

// block b: exclusive scan of its 1024 deg entries + block offset
__global__ __launch_bounds__(256) void scan_final(const int* __restrict__ deg,
                                                  const int* __restrict__ partials,
                                                  int* __restrict__ row_start,
                                                  int* __restrict__ cursor,
                                                  int n) {
    __shared__ int sbuf[256];
    int t = threadIdx.x;
    int base = blockIdx.x * 1024 + t * 4;
    int v[4];
#pragma unroll
    for (int j = 0; j < 4; ++j) v[j] = (base + j < n) ? deg[base + j] : 0;
    int tsum = v[0] + v[1] + v[2] + v[3];
    sbuf[t] = tsum;
    __syncthreads();
    // Hillis-Steele inclusive over 256
    for (int off = 1; off < 256; off <<= 1) {
        int tmp = (t >= off) ? sbuf[t - off] : 0;
        __syncthreads();
        sbuf[t] += tmp;
        __syncthreads();
    }
    int toff = partials[blockIdx.x] + sbuf[t] - tsum;   // exclusive thread offset
    int run = 0;
#pragma unroll
    for (int j = 0; j < 4; ++j) {
        int i = base + j;
        if (i < n) {
            int ex = toff + run;
            row_start[i] = ex;
            cursor[i] = ex;
        }
        run += v[j];
    }
}

__global__ __launch_bounds__(256) void scatter_kernel(const int* __restrict__ ei,
                                                      int* __restrict__ cursor,
                                                      int* __restrict__ csr_src,
                                                      int E) {
    int e = blockIdx.x * 256 + threadIdx.x;
    if (e >= E) return;
    int s = ei[e];
    int d = ei[E + e];
    int pos = atomicAdd(&cursor[d], 1);
    csr_src[pos] = s;
}

// ---------------- GEMM 128x128: register-blocked 4 rows x 8 cols ----------------

__global__ __launch_bounds__(256) void gemm128(const float* __restrict__ A,
                                               const float* __restrict__ W,
                                               float* __restrict__ out,
                                               int n) {
    __shared__ float xs[128][65];   // transposed: xs[k][row], pad 65
    __shared__ float ws[32][128];
    int tid = threadIdx.x;
    int row0 = blockIdx.x * 64;
    int rg = tid & 15;              // row group: rows rg*4 .. rg*4+3
    int cg = tid >> 4;              // col group: cols cg*8 .. cg*8+7

    // stage x tile transposed
    for (int idx = tid; idx < 64 * 32; idx += 256) {
        int r = idx >> 5, c4 = idx & 31;
        float4 v = make_float4(0.f, 0.f, 0.f, 0.f);
        if (row0 + r < n) v = *(const float4*)&A[(size_t)(row0 + r) * FDIM + c4 * 4];
        xs[c4 * 4 + 0][r] = v.x;
        xs[c4 * 4 + 1][r] = v.y;
        xs[c4 * 4 + 2][r] = v.z;
        xs[c4 * 4 + 3][r] = v.w;
    }

    float acc[4][8];
#pragma unroll
    for (int r = 0; r < 4; ++r)
#pragma unroll
        for (int c = 0; c < 8; ++c) acc[r][c] = 0.f;

    for (int kc = 0; kc < 128; kc += 32) {
        __syncthreads();
        for (int idx = tid; idx < 32 * 32; idx += 256) {
            int kk = idx >> 5, c4 = idx & 31;
            *(float4*)&ws[kk][c4 * 4] = *(const float4*)&W[(size_t)(kc + kk) * 128 + c4 * 4];
        }
        __syncthreads();
#pragma unroll
        for (int k = 0; k < 32; ++k) {
            float4 xv = *(const float4*)&xs[kc + k][rg * 4];
            float4 wa = *(const float4*)&ws[k][cg * 8];
            float4 wb = *(const float4*)&ws[k][cg * 8 + 4];
            float xr[4] = {xv.x, xv.y, xv.z, xv.w};
            float wc[8] = {wa.x, wa.y, wa.z, wa.w, wb.x, wb.y, wb.z, wb.w};
#pragma unroll
            for (int r = 0; r < 4; ++r)
#pragma unroll
                for (int c = 0; c < 8; ++c)
                    acc[r][c] += xr[r] * wc[c];
        }
    }

#pragma unroll
    for (int r = 0; r < 4; ++r) {
        int row = row0 + rg * 4 + r;
        if (row < n) {
            float4 a = make_float4(acc[r][0], acc[r][1], acc[r][2], acc[r][3]);
            float4 b = make_float4(acc[r][4], acc[r][5], acc[r][6], acc[r][7]);
            *(float4*)&out[(size_t)row * FDIM + cg * 8] = a;
            *(float4*)&out[(size_t)row * FDIM + cg * 8 + 4] = b;
        }
    }
}

// ---------------- classifier GEMM: A[n x 128] @ Wc[128 x 40] + bc ----------------

__global__ __launch_bounds__(256) void gemm_cls(const float* __restrict__ A,
                                                const float* __restrict__ W,
                                                const float* __restrict__ bias,
                                                float* __restrict__ out,
                                                int n) {
    constexpr int M = 40, CG = 10;
    __shared__ float xs[64][129];
    __shared__ float ws[32][M];
    int tid = threadIdx.x;
    int row0 = blockIdx.x * 64;
    int row = tid & 63;
    int col0 = (tid >> 6) * CG;

    for (int idx = tid; idx < 64 * 32; idx += 256) {
        int r = idx >> 5, c4 = idx & 31;
        float4 v = make_float4(0.f, 0.f, 0.f, 0.f);
        if (row0 + r < n) v = *(const float4*)&A[(size_t)(row0 + r) * FDIM + c4 * 4];
        *(float4*)&xs[r][c4 * 4] = v;
    }

    float acc[CG];
#pragma unroll
    for (int j = 0; j < CG; ++j) acc[j] = 0.f;

    for (int kc = 0; kc < 128; kc += 32) {
        __syncthreads();
        for (int idx = tid; idx < 32 * M; idx += 256) {
            int kk = idx / M, c = idx % M;
            ws[kk][c] = W[(size_t)(kc + kk) * M + c];
        }
        __syncthreads();
#pragma unroll
        for (int k = 0; k < 32; ++k) {
            float xv = xs[row][kc + k];
#pragma unroll
            for (int j = 0; j < CG; ++j)
                acc[j] += xv * ws[k][col0 + j];
        }
    }

    if (row0 + row < n) {
#pragma unroll
        for (int j = 0; j < CG; ++j)
            out[(size_t)(row0 + row) * M + col0 + j] = acc[j] + bias[col0 + j];
    }
}

// ---------------- attention logits ----------------

__global__ __launch_bounds__(256) void al_kernel(const float* __restrict__ hx,
                                                 const float* __restrict__ a_src,
                                                 const float* __restrict__ a_dst,
                                                 float* __restrict__ als,
                                                 float* __restrict__ ald,
                                                 int n) {
    int t = blockIdx.x * 256 + threadIdx.x;
    if (t >= n * HEADS) return;
    int node = t >> 3, h = t & 7;
    float ss = 0.f, sd = 0.f;
#pragma unroll
    for (int d = 0; d < DHEAD; d += 4) {
        float4 hv = *(const float4*)&hx[(size_t)node * FDIM + h * DHEAD + d];
        float4 as = *(const float4*)&a_src[h * DHEAD + d];
        float4 ad = *(const float4*)&a_dst[h * DHEAD + d];
        ss += hv.x * as.x + hv.y * as.y + hv.z * as.z + hv.w * as.w;
        sd += hv.x * ad.x + hv.y * ad.y + hv.z * ad.z + hv.w * ad.w;
    }
    als[t] = ss;
    ald[t] = sd;
}

// ---------------- per-node segment softmax + aggregation ----------------
// One wave per dst node. Phase B: weights for 8 edges x 8 heads computed in
// parallel across 64 lanes (1 expf per lane per 8 edges), shuffle-broadcast.

template <bool DOELU>
__global__ __launch_bounds__(256) void gat_aggregate(const float* __restrict__ hx,
                                                     const float* __restrict__ als,
                                                     const float* __restrict__ ald,
                                                     const int* __restrict__ row_start,
                                                     const int* __restrict__ csr_src,
                                                     const float* __restrict__ bias,
                                                     float* __restrict__ out,
                                                     int n) {
    int wid = threadIdx.x >> 6;
    int lane = threadIdx.x & 63;
    int node = blockIdx.x * 4 + wid;
    if (node >= n) return;

    int rs = row_start[node];
    int deg = row_start[node + 1] - rs;

    int h = lane & 7;            // head this lane owns for max/weights
    int h0 = lane >> 4;          // head for col = lane
    float ald_h = ald[node * HEADS + h];

    // ---- phase A: per-head running max (self loop + edges) ----
    float mmax = leaky02(als[node * HEADS + h] + ald_h);
    for (int i = lane >> 3; i < deg; i += 8)
        mmax = fmaxf(mmax, leaky02(als[csr_src[rs + i] * HEADS + h] + ald_h));
    mmax = fmaxf(mmax, __shfl_xor(mmax, 8));
    mmax = fmaxf(mmax, __shfl_xor(mmax, 16));
    mmax = fmaxf(mmax, __shfl_xor(mmax, 32));
    float m_h = mmax;            // max for head h, in every lane with this h

    // ---- phase B: chunks of 8 edges; edge index `deg` == self loop ----
    float acc0 = 0.f, acc1 = 0.f, z0 = 0.f, z1 = 0.f;
    int total = deg + 1;
    int i0 = 0;
    for (; i0 + 8 <= total; i0 += 8) {
        int ii = i0 + (lane >> 3);
        int srcv = (ii < deg) ? csr_src[rs + ii] : node;
        float w = __expf(leaky02(als[srcv * HEADS + h] + ald_h) - m_h);
#pragma unroll
        for (int e = 0; e < 8; ++e) {
            int s    = __shfl(srcv, e * 8);
            float w0 = __shfl(w, e * 8 + h0);
            float w1 = __shfl(w, e * 8 + 4 + h0);
            z0 += w0;
            z1 += w1;
            acc0 += w0 * hx[(size_t)s * FDIM + lane];
            acc1 += w1 * hx[(size_t)s * FDIM + 64 + lane];
        }
    }
    {   // tail chunk (1..8 edges incl. self loop)
        int ii = i0 + (lane >> 3);
        int srcv = node;
        if (ii < deg) srcv = csr_src[rs + ii];
        float w = 0.f;
        if (ii < total) w = __expf(leaky02(als[srcv * HEADS + h] + ald_h) - m_h);
        int rem = total - i0;
        for (int e = 0; e < rem; ++e) {
            int s    = __shfl(srcv, e * 8);
            float w0 = __shfl(w, e * 8 + h0);
            float w1 = __shfl(w, e * 8 + 4 + h0);
            z0 += w0;
            z1 += w1;
            acc0 += w0 * hx[(size_t)s * FDIM + lane];
            acc1 += w1 * hx[(size_t)s * FDIM + 64 + lane];
        }
    }

    float o0 = acc0 / z0 + bias[lane];
    float o1 = acc1 / z1 + bias[64 + lane];
    if (DOELU) {
        o0 = o0 > 0.f ? o0 : (__expf(o0) - 1.f);
        o1 = o1 > 0.f ? o1 : (__expf(o1) - 1.f);
    }
    out[(size_t)node * FDIM + lane] = o0;
    out[(size_t)node * FDIM + 64 + lane] = o1;
}

// ---------------- launch ----------------

extern "C" void kernel_launch(void* const* d_in, const int* in_sizes, int n_in,
                              void* d_out, int out_size, void* d_ws, size_t ws_size,
                              hipStream_t stream) {
    const float* x      = (const float*)d_in[0];
    const int*   ei     = (const int*)d_in[1];   // int32 [2][E]
    const float* W1     = (const float*)d_in[2];
    const float* a_src1 = (const float*)d_in[3];
    const float* a_dst1 = (const float*)d_in[4];
    const float* b1     = (const float*)d_in[5];
    const float* W2     = (const float*)d_in[6];
    const float* a_src2 = (const float*)d_in[7];
    const float* a_dst2 = (const float*)d_in[8];
    const float* b2     = (const float*)d_in[9];
    const float* Wc     = (const float*)d_in[10];
    const float* bc     = (const float*)d_in[11];
    float* out = (float*)d_out;

    const int N = in_sizes[0] / FDIM;     // 50000
    const int E = in_sizes[1] / 2;        // 800000
    const int NB = (N + 1023) / 1024;     // scan blocks (49)

    // workspace layout (16B-aligned segments)
    float* hx   = (float*)d_ws;                        // N*128
    float* hbuf = hx + (size_t)N * FDIM;               // N*128
    float* als  = hbuf + (size_t)N * FDIM;             // N*8
    float* ald  = als + (size_t)N * HEADS;             // N*8
    int* deg       = (int*)(ald + (size_t)N * HEADS);  // N
    int* cursor    = deg + N;                          // N
    int* row_start = cursor + N;                       // N+1 (+pad)
    int* partials  = row_start + ((N + 8) & ~3);       // NB
    int* csr_src   = partials + ((NB + 4) & ~3);       // E

    // ---- CSR by dst (shared by both layers) ----
    hipMemsetAsync(deg, 0, (size_t)N * sizeof(int), stream);
    hist_kernel<<<(E + 255) / 256, 256, 0, stream>>>(ei, deg, E);
    scan_partial<<<NB, 256, 0, stream>>>(deg, partials, N);
    scan_offsets<<<1, 64, 0, stream>>>(partials, row_start, NB, N);
    scan_final<<<NB, 256, 0, stream>>>(deg, partials, row_start, cursor, N);
    scatter_kernel<<<(E + 255) / 256, 256, 0, stream>>>(ei, cursor, csr_src, E);

    const int gemm_grid = (N + 63) / 64;
    const int al_grid   = (N * HEADS + 255) / 256;
    const int agg_grid  = (N + 3) / 4;

    // ---- layer 1 ----
    gemm128<<<gemm_grid, 256, 0, stream>>>(x, W1, hx, N);
    al_kernel<<<al_grid, 256, 0, stream>>>(hx, a_src1, a_dst1, als, ald, N);
    gat_aggregate<true><<<agg_grid, 256, 0, stream>>>(hx, als, ald, row_start,
                                                      csr_src, b1, hbuf, N);
    // ---- layer 2 ----
    gemm128<<<gemm_grid, 256, 0, stream>>>(hbuf, W2, hx, N);
    al_kernel<<<al_grid, 256, 0, stream>>>(hx, a_src2, a_dst2, als, ald, N);
    gat_aggregate<false><<<agg_grid, 256, 0, stream>>>(hx, als, ald, row_start,
                                                       csr_src, b2, hbuf, N);
    // ---- classifier ----
    gemm_cls<<<gemm_grid, 256, 0, stream>>>(hbuf, Wc, bc, out, N);
}